// Round 1
// baseline (1579.107 us; speedup 1.0000x reference)
//
#include <hip/hip_runtime.h>
#include <cstdint>
#include <math.h>

static constexpr int Bc = 2, Tc = 2048, Cch = 512, Hc = 8, HDc = 64, KTOP = 64;
static constexpr int BT = Bc * Tc;  // 4096

__device__ inline float wave_sum_f(float x) {
#pragma unroll
  for (int o = 32; o; o >>= 1) x += __shfl_xor(x, o);
  return x;
}
__device__ inline float wave_max_f(float x) {
#pragma unroll
  for (int o = 32; o; o >>= 1) x = fmaxf(x, __shfl_xor(x, o));
  return x;
}
__device__ inline int wave_sum_i(int x) {
#pragma unroll
  for (int o = 32; o; o >>= 1) x += __shfl_xor(x, o);
  return x;
}

// Out[M,N] = A[M,K] @ W[K,N] + bias[N];  M=4096, N=K=512
__global__ __launch_bounds__(256) void gemm_bias_k(
    const float* __restrict__ A, const float* __restrict__ W,
    const float* __restrict__ bias, float* __restrict__ Out)
{
  constexpr int M = BT, N = Cch, K = Cch;
  constexpr int BM = 64, BN = 64, BK = 16;
  __shared__ float As[BK][BM + 1];
  __shared__ float Ws[BK][BN + 1];
  const int tid = threadIdx.x;
  const int tx = tid & 15, ty = tid >> 4;
  const int brow = blockIdx.y * BM, bcol = blockIdx.x * BN;
  float acc[4][4] = {};
  for (int k0 = 0; k0 < K; k0 += BK) {
#pragma unroll
    for (int i = 0; i < (BM * BK) / 256; i++) {
      int idx = tid + i * 256;
      int r = idx / BK, c = idx % BK;
      As[c][r] = A[(size_t)(brow + r) * K + (k0 + c)];
    }
#pragma unroll
    for (int i = 0; i < (BK * BN) / 256; i++) {
      int idx = tid + i * 256;
      int r = idx / BN, c = idx % BN;
      Ws[r][c] = W[(size_t)(k0 + r) * N + (bcol + c)];
    }
    __syncthreads();
#pragma unroll
    for (int kk = 0; kk < BK; kk++) {
      float a[4], b[4];
#pragma unroll
      for (int i = 0; i < 4; i++) a[i] = As[kk][ty * 4 + i];
#pragma unroll
      for (int j = 0; j < 4; j++) b[j] = Ws[kk][tx * 4 + j];
#pragma unroll
      for (int i = 0; i < 4; i++)
#pragma unroll
        for (int j = 0; j < 4; j++) acc[i][j] += a[i] * b[j];
    }
    __syncthreads();
  }
#pragma unroll
  for (int i = 0; i < 4; i++) {
    int r = brow + ty * 4 + i;
#pragma unroll
    for (int j = 0; j < 4; j++) {
      int col = bcol + tx * 4 + j;
      Out[(size_t)r * N + col] = acc[i][j] + bias[col];
    }
  }
}

// normalize each (token, head) 64-vector of V in place
__global__ __launch_bounds__(256) void vnorm_k(float* __restrict__ V)
{
  int gid = blockIdx.x * 256 + threadIdx.x;
  int w = gid >> 6;
  int lane = gid & 63;
  float v = V[(size_t)w * 64 + lane];
  float ss = wave_sum_f(v * v);
  float nrm = fmaxf(sqrtf(ss), 1e-12f);
  V[(size_t)w * 64 + lane] = v / nrm;
}

// one wave per query row: scores, exact top-64 threshold, softmax, PV
__global__ __launch_bounds__(256) void attn_k(
    const float* __restrict__ Q, const float* __restrict__ K,
    const float* __restrict__ V, float* __restrict__ Y)
{
  __shared__ float w_lds[4][Tc];
  __shared__ float q_lds[4][HDc];
  const int wave = threadIdx.x >> 6, lane = threadIdx.x & 63;
  const int wid = blockIdx.x * 4 + wave;
  const int t = wid % Tc;
  const int h = (wid / Tc) % Hc;
  const int b = wid / (Tc * Hc);

  const float* qrow = Q + ((size_t)(b * Tc + t)) * Cch + h * HDc;
  q_lds[wave][lane] = qrow[lane];
  // single-wave producer/consumer on this LDS slice: program order suffices

  const float* Khead = K + ((size_t)b * Tc) * Cch + h * HDc;

  float s[32];
#pragma unroll
  for (int i = 0; i < 32; i++) {
    int j = i * 64 + lane;
    if (j <= t) {
      const float4* krow = reinterpret_cast<const float4*>(Khead + (size_t)j * Cch);
      float acc = 0.f;
#pragma unroll
      for (int dd = 0; dd < 16; dd++) {
        float4 kv = krow[dd];
        acc += q_lds[wave][dd * 4 + 0] * kv.x;
        acc += q_lds[wave][dd * 4 + 1] * kv.y;
        acc += q_lds[wave][dd * 4 + 2] * kv.z;
        acc += q_lds[wave][dd * 4 + 3] * kv.w;
      }
      s[i] = acc * 0.125f;  // 1/sqrt(64)
    } else {
      s[i] = -INFINITY;
    }
  }

  // order-preserving uint mapping for exact radix select of 64th largest
  unsigned su[32];
#pragma unroll
  for (int i = 0; i < 32; i++) {
    unsigned u = __float_as_uint(s[i]);
    su[i] = (u & 0x80000000u) ? ~u : (u | 0x80000000u);
  }
  unsigned lo = 0;
  for (int bit = 31; bit >= 0; bit--) {
    unsigned cand = lo | (1u << bit);
    int cnt = 0;
#pragma unroll
    for (int i = 0; i < 32; i++) cnt += (su[i] >= cand) ? 1 : 0;
    cnt = wave_sum_i(cnt);
    if (cnt >= KTOP) lo = cand;  // max v with count(>=v) >= 64 == kth largest
  }

  float m = -INFINITY;
#pragma unroll
  for (int i = 0; i < 32; i++) m = fmaxf(m, s[i]);
  m = wave_max_f(m);

  float sum = 0.f;
#pragma unroll
  for (int i = 0; i < 32; i++) {
    float wv = 0.f;
    if (su[i] >= lo) wv = __expf(s[i] - m);  // exp(-inf)=0 handles short rows
    w_lds[wave][i * 64 + lane] = wv;
    sum += wv;
  }
  sum = wave_sum_f(sum);
  const float inv = 1.0f / sum;

  const float* Vhead = V + ((size_t)b * Tc) * Cch + h * HDc;
  float y = 0.f;
  for (int j = 0; j <= t; j++) {
    float wj = w_lds[wave][j];  // wave-uniform broadcast
    if (wj != 0.f) {
      y += wj * Vhead[(size_t)j * Cch + lane];
    }
  }
  Y[((size_t)(b * Tc + t)) * Cch + h * HDc + lane] = y * inv;
}

extern "C" void kernel_launch(void* const* d_in, const int* in_sizes, int n_in,
                              void* d_out, int out_size, void* d_ws, size_t ws_size,
                              hipStream_t stream)
{
  const float* q  = (const float*)d_in[0];
  // d_in[1] = tgt_mask: pure causal tril, handled analytically
  const float* Wq = (const float*)d_in[2];
  const float* bq = (const float*)d_in[3];
  const float* Wk = (const float*)d_in[4];
  const float* bk = (const float*)d_in[5];
  const float* Wv = (const float*)d_in[6];
  const float* bv = (const float*)d_in[7];
  const float* Wp = (const float*)d_in[8];
  const float* bp = (const float*)d_in[9];
  float* out = (float*)d_out;
  float* ws  = (float*)d_ws;

  constexpr size_t NEL = (size_t)BT * Cch;  // 2M floats per buffer
  float* Qp = ws;
  float* Kp = ws + NEL;
  float* Vp = ws + 2 * NEL;
  float* Yb = ws + 3 * NEL;

  dim3 gg(Cch / 64, BT / 64);  // (8, 64)
  gemm_bias_k<<<gg, 256, 0, stream>>>(q, Wq, bq, Qp);
  gemm_bias_k<<<gg, 256, 0, stream>>>(q, Wk, bk, Kp);
  gemm_bias_k<<<gg, 256, 0, stream>>>(q, Wv, bv, Vp);
  vnorm_k<<<(BT * Hc * 64) / 256, 256, 0, stream>>>(Vp);
  attn_k<<<(Bc * Hc * Tc) / 4, 256, 0, stream>>>(Qp, Kp, Vp, Yb);
  gemm_bias_k<<<gg, 256, 0, stream>>>(Yb, Wp, bp, out);
}

// Round 3
// 677.496 us; speedup vs baseline: 2.3308x; 2.3308x over previous
//
#include <hip/hip_runtime.h>
#include <hip/hip_bf16.h>
#include <cstdint>
#include <math.h>

static constexpr int Bc = 2, Tc = 2048, Cch = 512, Hc = 8, HDc = 64;
static constexpr int BT = Bc * Tc;  // 4096

typedef float f32x4 __attribute__((ext_vector_type(4)));
typedef short s16x8 __attribute__((ext_vector_type(8)));

__device__ inline float wave_sum_f(float x) {
#pragma unroll
  for (int o = 32; o; o >>= 1) x += __shfl_xor(x, o);
  return x;
}
__device__ inline float wave_max_f(float x) {
#pragma unroll
  for (int o = 32; o; o >>= 1) x = fmaxf(x, __shfl_xor(x, o));
  return x;
}
__device__ inline short f2bf(float x) {  // RNE f32->bf16, finite inputs only
  unsigned u = __float_as_uint(x);
  unsigned r = (u + 0x7FFFu + ((u >> 16) & 1u)) >> 16;
  return (short)r;
}

// ---------------- projection GEMM: Out[M,N] = A[M,K] @ W[K,N] + bias ----------------
template <int BF16OUT>
__global__ __launch_bounds__(256) void gemm_bias_k(
    const float* __restrict__ A, const float* __restrict__ W,
    const float* __restrict__ bias, void* __restrict__ OutV)
{
  constexpr int N = Cch, K = Cch;
  constexpr int BM = 64, BN = 64, BK = 16;
  __shared__ float As[BK][BM + 1];
  __shared__ float Ws[BK][BN + 1];
  const int tid = threadIdx.x;
  const int tx = tid & 15, ty = tid >> 4;
  const int brow = blockIdx.y * BM, bcol = blockIdx.x * BN;
  float acc[4][4] = {};
  for (int k0 = 0; k0 < K; k0 += BK) {
#pragma unroll
    for (int i = 0; i < (BM * BK) / 256; i++) {
      int idx = tid + i * 256;
      int r = idx / BK, c = idx % BK;
      As[c][r] = A[(size_t)(brow + r) * K + (k0 + c)];
    }
#pragma unroll
    for (int i = 0; i < (BK * BN) / 256; i++) {
      int idx = tid + i * 256;
      int r = idx / BN, c = idx % BN;
      Ws[r][c] = W[(size_t)(k0 + r) * N + (bcol + c)];
    }
    __syncthreads();
#pragma unroll
    for (int kk = 0; kk < BK; kk++) {
      float a[4], b[4];
#pragma unroll
      for (int i = 0; i < 4; i++) a[i] = As[kk][ty * 4 + i];
#pragma unroll
      for (int j = 0; j < 4; j++) b[j] = Ws[kk][tx * 4 + j];
#pragma unroll
      for (int i = 0; i < 4; i++)
#pragma unroll
        for (int j = 0; j < 4; j++) acc[i][j] += a[i] * b[j];
    }
    __syncthreads();
  }
#pragma unroll
  for (int i = 0; i < 4; i++) {
    int r = brow + ty * 4 + i;
#pragma unroll
    for (int j = 0; j < 4; j++) {
      int col = bcol + tx * 4 + j;
      float v = acc[i][j] + bias[col];
      if (BF16OUT) ((unsigned short*)OutV)[(size_t)r * N + col] = (unsigned short)f2bf(v);
      else         ((float*)OutV)[(size_t)r * N + col] = v;
    }
  }
}

// normalize each (token, head) 64-vector of V; f32 in, bf16 out
__global__ __launch_bounds__(256) void vnorm_k(const float* __restrict__ V,
                                               unsigned short* __restrict__ Vo)
{
  int gid = blockIdx.x * 256 + threadIdx.x;
  int w = gid >> 6;
  int lane = gid & 63;
  float v = V[(size_t)w * 64 + lane];
  float ss = wave_sum_f(v * v);
  float nrm = fmaxf(sqrtf(ss), 1e-12f);
  Vo[(size_t)w * 64 + lane] = (unsigned short)f2bf(v / nrm);
}

// ---------------- fused attention: block = (b, h, 16 query rows) ----------------
static constexpr int S_STRIDE = 2052;                 // f32 elems per S row (+4 pad)
static constexpr int OFF_S = 0;                       // 16*2052*4 = 131328
static constexpr int OFF_Q = 131328;                  // 16*72*2   = 2304
static constexpr int OFF_KV = 133632;                 // Ks 128*72*2=18432 | Vs 8192
static constexpr int OFF_SCR = OFF_KV + 8192;         // 4096 (phase-3 tail, disjoint from Vs)
static constexpr int OFF_FLAGS = 152064;              // 32*4
static constexpr int OFF_INV = 152192;                // 16*4
static constexpr int LDS_BYTES = 152320;

__global__ __launch_bounds__(512) void attn2_k(
    const unsigned short* __restrict__ Qp, const unsigned short* __restrict__ Kp,
    const unsigned short* __restrict__ Vn, float* __restrict__ Yb)
{
  extern __shared__ char smem[];
  float* S    = (float*)(smem + OFF_S);
  int* flags  = (int*)(smem + OFF_FLAGS);
  float* invl = (float*)(smem + OFF_INV);

  const int tid = threadIdx.x;
  const int w = tid >> 6, lane = tid & 63;
  const int e = lane >> 4, lr = lane & 15;
  const int qt = (int)(gridDim.x - 1) - (int)blockIdx.x;  // big tiles dispatch first
  const int h = blockIdx.y, b = blockIdx.z;
  const int trow0 = qt * 16;
  const int ncols = min((trow0 + 16 + 127) & ~127, Tc);
  const int nI = ncols >> 6;   // 64-col slots / PV tiles
  const int nKT = ncols >> 7;  // 128-key staging tiles

  // ---- phase 0: stage Q tile (bf16), init flags ----
  if (tid < 128) {
    int row = tid >> 3, ch = tid & 7;
    const unsigned short* g = Qp + ((size_t)(b * Tc + trow0 + row)) * Cch + h * HDc + ch * 8;
    *(uint4*)(smem + OFF_Q + row * 144 + ch * 16) = *(const uint4*)g;
  } else if (tid < 160) {
    flags[tid - 128] = 0;
  }
  __syncthreads();

  // ---- phase 1: S = (Q K^T) * 1/8 via MFMA ----
  for (int kt = 0; kt < nKT; kt++) {
#pragma unroll
    for (int p = 0; p < 2; p++) {
      int idx = p * 512 + tid;
      int key = idx >> 3, ch = idx & 7;
      const unsigned short* g = Kp + ((size_t)(b * Tc + kt * 128 + key)) * Cch + h * HDc + ch * 8;
      *(uint4*)(smem + OFF_KV + key * 144 + ch * 16) = *(const uint4*)g;
    }
    __syncthreads();
    f32x4 acc = {0.f, 0.f, 0.f, 0.f};
#pragma unroll
    for (int kh = 0; kh < 2; kh++) {
      s16x8 a = *(const s16x8*)(smem + OFF_Q + lr * 144 + kh * 64 + e * 16);
      s16x8 bb = *(const s16x8*)(smem + OFF_KV + (w * 16 + lr) * 144 + kh * 64 + e * 16);
      acc = __builtin_amdgcn_mfma_f32_16x16x32_bf16(a, bb, acc, 0, 0, 0);
    }
#pragma unroll
    for (int r = 0; r < 4; r++) {
      int row = e * 4 + r;  // C/D: col=lane&15, row=(lane>>4)*4+reg
      S[row * S_STRIDE + kt * 128 + w * 16 + lr] = acc[r] * 0.125f;
    }
    __syncthreads();
  }

  // ---- phase 2: exact top-64 select + softmax weights (2 rows per wave) ----
#pragma unroll 1
  for (int rr = 0; rr < 2; rr++) {
    const int row = w * 2 + rr;
    const int t = trow0 + row;
    float vals[32];
    unsigned su[32];
#pragma unroll
    for (int i = 0; i < 32; i++) {
      float v = -INFINITY;
      if (i < nI) {
        int j = i * 64 + lane;
        float sv = S[row * S_STRIDE + j];
        v = (j <= t) ? sv : -INFINITY;
      }
      vals[i] = v;
      unsigned u = __float_as_uint(v);
      su[i] = (u & 0x80000000u) ? ~u : (u | 0x80000000u);
    }
    // radix search: max lo with count(su >= lo) >= 64  (== 64th largest, exact ties)
    unsigned lo = 0;
    for (int bit = 31; bit >= 0; bit--) {
      unsigned cand = lo | (1u << bit);
      int cnt = 0;
#pragma unroll
      for (int i = 0; i < 32; i++)
        cnt += (int)__popcll(__ballot(su[i] >= cand));
      if (cnt >= 64) lo = cand;
    }
    float m = -INFINITY;
#pragma unroll
    for (int i = 0; i < 32; i++) m = fmaxf(m, vals[i]);
    m = wave_max_f(m);
    float sum = 0.f;
#pragma unroll
    for (int i = 0; i < 32; i++) {
      float wv = (su[i] >= lo) ? __expf(vals[i] - m) : 0.f;  // exp(-inf)=0
      sum += wv;
      if (i < nI) {
        S[row * S_STRIDE + i * 64 + lane] = wv;
        if (__any(wv > 0.f) && lane == 0) flags[i] = 1;  // benign race (writes 1)
      }
    }
    sum = wave_sum_f(sum);
    if (lane == 0) invl[row] = 1.0f / sum;
  }
  __syncthreads();

  // ---- phase 3: Y = P @ Vn via MFMA over flagged 64-key tiles ----
  const int dt = w & 3, kh = w >> 2;
  f32x4 accp = {0.f, 0.f, 0.f, 0.f};
  for (int t2 = 0; t2 < nI; t2++) {
    if (!flags[t2]) continue;  // uniform across block
    {
      int key = tid >> 3, ch = tid & 7;
      const unsigned short* g = Vn + ((size_t)(b * Tc + t2 * 64 + key)) * Cch + h * HDc + ch * 8;
      *(uint4*)(smem + OFF_KV + (ch >> 1) * 2048 + key * 32 + (ch & 1) * 16) = *(const uint4*)g;
    }
    __syncthreads();
    const int kb = t2 * 64 + kh * 32 + e * 8;
    f32x4 p0 = *(const f32x4*)(&S[lr * S_STRIDE + kb]);
    f32x4 p1 = *(const f32x4*)(&S[lr * S_STRIDE + kb + 4]);
    s16x8 a;
    a[0] = f2bf(p0[0]); a[1] = f2bf(p0[1]); a[2] = f2bf(p0[2]); a[3] = f2bf(p0[3]);
    a[4] = f2bf(p1[0]); a[5] = f2bf(p1[1]); a[6] = f2bf(p1[2]); a[7] = f2bf(p1[3]);
    s16x8 bv;
#pragma unroll
    for (int j = 0; j < 8; j++)
      bv[j] = *(const short*)(smem + OFF_KV + dt * 2048 + (kh * 32 + e * 8 + j) * 32 + lr * 2);
    accp = __builtin_amdgcn_mfma_f32_16x16x32_bf16(a, bv, accp, 0, 0, 0);
    __syncthreads();
  }
  if (w >= 4) {
    *(f32x4*)(smem + OFF_SCR + (w - 4) * 1024 + lane * 16) = accp;
  }
  __syncthreads();
  if (w < 4) {
    f32x4 o = *(const f32x4*)(smem + OFF_SCR + w * 1024 + lane * 16);
#pragma unroll
    for (int r = 0; r < 4; r++) {
      int row = e * 4 + r;
      float y = (accp[r] + o[r]) * invl[row];
      Yb[((size_t)(b * Tc + trow0 + row)) * Cch + h * HDc + dt * 16 + lr] = y;
    }
  }
}

extern "C" void kernel_launch(void* const* d_in, const int* in_sizes, int n_in,
                              void* d_out, int out_size, void* d_ws, size_t ws_size,
                              hipStream_t stream)
{
  const float* q  = (const float*)d_in[0];
  // d_in[1] = tgt_mask: pure causal tril, handled analytically
  const float* Wq = (const float*)d_in[2];
  const float* bq = (const float*)d_in[3];
  const float* Wk = (const float*)d_in[4];
  const float* bk = (const float*)d_in[5];
  const float* Wv = (const float*)d_in[6];
  const float* bv = (const float*)d_in[7];
  const float* Wp = (const float*)d_in[8];
  const float* bp = (const float*)d_in[9];
  float* out = (float*)d_out;
  char* ws = (char*)d_ws;

  unsigned short* Qp = (unsigned short*)(ws);                          // 4 MB
  unsigned short* Kp = (unsigned short*)(ws + (4u << 20));             // 4 MB
  float*          Vf = (float*)(ws + (8u << 20));                      // 8 MB
  unsigned short* Vn = (unsigned short*)(ws + (16u << 20));            // 4 MB
  float*          Yb = (float*)(ws + (20u << 20));                     // 8 MB

  dim3 gg(Cch / 64, BT / 64);  // (8, 64)
  gemm_bias_k<1><<<gg, 256, 0, stream>>>(q, Wq, bq, Qp);
  gemm_bias_k<1><<<gg, 256, 0, stream>>>(q, Wk, bk, Kp);
  gemm_bias_k<0><<<gg, 256, 0, stream>>>(q, Wv, bv, Vf);
  vnorm_k<<<(BT * Cch) / 256, 256, 0, stream>>>(Vf, Vn);  // 8192 blocks: 1 thread/element

  hipFuncSetAttribute((const void*)attn2_k, hipFuncAttributeMaxDynamicSharedMemorySize, LDS_BYTES);
  attn2_k<<<dim3(Tc / 16, Hc, Bc), 512, LDS_BYTES, stream>>>(Qp, Kp, Vn, Yb);

  gemm_bias_k<0><<<gg, 256, 0, stream>>>(Yb, Wp, bp, out);
}

// Round 5
// 253.059 us; speedup vs baseline: 6.2401x; 2.6772x over previous
//
#include <hip/hip_runtime.h>
#include <cstdint>
#include <math.h>

static constexpr int Bc = 2, Tc = 2048, Cch = 512, Hc = 8;
static constexpr int BT = Bc * Tc;          // 4096
static constexpr int NBH = Bc * Hc;         // 16
static constexpr int NRT = Tc / 128;        // 16 row-tiles per (b,h)
static constexpr int NTRI = NRT * (NRT + 1) / 2;  // 136 causal blocks
static constexpr size_t TRI_FLOATS = (size_t)NTRI * 16384;  // f32 per (b,h)

typedef float f32x4 __attribute__((ext_vector_type(4)));
typedef short s16x8 __attribute__((ext_vector_type(8)));
typedef unsigned short u16x8 __attribute__((ext_vector_type(8)));
typedef unsigned short u16x4 __attribute__((ext_vector_type(4)));

__device__ __host__ inline constexpr int tri_i(int r) { return r * (r + 1) / 2; }

__device__ inline float wave_sum_f(float x) {
#pragma unroll
  for (int o = 32; o; o >>= 1) x += __shfl_xor(x, o);
  return x;
}
__device__ inline unsigned short f2bf(float x) {  // RNE f32->bf16 (finite)
  unsigned u = __float_as_uint(x);
  return (unsigned short)((u + 0x7FFFu + ((u >> 16) & 1u)) >> 16);
}
__device__ inline float bf2f(unsigned short h) { return __uint_as_float(((unsigned)h) << 16); }
__device__ inline float su2f(unsigned s) {  // inverse order-preserving map
  unsigned u = (s & 0x80000000u) ? (s ^ 0x80000000u) : ~s;
  return __uint_as_float(u);
}

// ---------- split f32 -> bf16 hi/lo ----------
__global__ __launch_bounds__(256) void split_k(const float* __restrict__ X,
    unsigned short* __restrict__ hi, unsigned short* __restrict__ lo, int n8) {
  int i = blockIdx.x * 256 + threadIdx.x;
  if (i >= n8) return;
  const f32x4* p = (const f32x4*)X + (size_t)i * 2;
  f32x4 a = p[0], b = p[1];
  float v[8] = {a[0], a[1], a[2], a[3], b[0], b[1], b[2], b[3]};
  u16x8 h, l;
#pragma unroll
  for (int c = 0; c < 8; c++) {
    unsigned short hh = f2bf(v[c]);
    h[c] = hh;
    l[c] = f2bf(v[c] - bf2f(hh));
  }
  *(u16x8*)(hi + (size_t)i * 8) = h;
  *(u16x8*)(lo + (size_t)i * 8) = l;
}

// ---------- split + transpose weights: W[k][n] f32 -> WT[n][k] bf16 hi/lo ----------
__global__ __launch_bounds__(256) void splitT_k(const float* __restrict__ W,
    unsigned short* __restrict__ hiT, unsigned short* __restrict__ loT) {
  __shared__ float t[64][65];
  const int tid = threadIdx.x;
  const int k0 = blockIdx.x * 64, n0 = blockIdx.y * 64;
#pragma unroll
  for (int p = 0; p < 4; p++) {
    int idx = tid + p * 256, kk = idx >> 4, n4 = idx & 15;
    f32x4 v = *(const f32x4*)&W[(size_t)(k0 + kk) * Cch + n0 + n4 * 4];
    t[kk][n4 * 4 + 0] = v[0]; t[kk][n4 * 4 + 1] = v[1];
    t[kk][n4 * 4 + 2] = v[2]; t[kk][n4 * 4 + 3] = v[3];
  }
  __syncthreads();
  // write phase: exactly 64 n-values x 4 k-segments = 256 items, ONE pass
  {
    int n = tid >> 2, ks = tid & 3;
    u16x8 h0, h1, l0, l1;
#pragma unroll
    for (int kk = 0; kk < 8; kk++) {
      float x = t[ks * 16 + kk][n];
      unsigned short hh = f2bf(x);
      h0[kk] = hh; l0[kk] = f2bf(x - bf2f(hh));
      float y = t[ks * 16 + 8 + kk][n];
      unsigned short hy = f2bf(y);
      h1[kk] = hy; l1[kk] = f2bf(y - bf2f(hy));
    }
    size_t base = (size_t)(n0 + n) * Cch + k0 + ks * 16;
    *(u16x8*)(hiT + base) = h0; *(u16x8*)(hiT + base + 8) = h1;
    *(u16x8*)(loT + base) = l0; *(u16x8*)(loT + base + 8) = l1;
  }
}

// ---------- bf16x3 MFMA GEMM: Out[M=4096][512] = (Ahi+Alo)@(BT)^T + bias ----------
template <int BF16OUT>
__global__ __launch_bounds__(256) void gemm3_k(
    const unsigned short* __restrict__ Ahi, const unsigned short* __restrict__ Alo,
    const unsigned short* __restrict__ Bhi, const unsigned short* __restrict__ Blo,
    const float* __restrict__ bias, void* __restrict__ Out) {
  __shared__ unsigned short Ah[2][64][72];
  __shared__ unsigned short Bs[2][64][72];
  const int tid = threadIdx.x;
  const int w = tid >> 6, lane = tid & 63, e = lane >> 4, lr = lane & 15;
  const int wr = w >> 1, wc = w & 1;
  const int brow = blockIdx.y * 64, bcol = blockIdx.x * 64;
  f32x4 acc[2][2] = {};
  for (int k0 = 0; k0 < Cch; k0 += 64) {
#pragma unroll
    for (int p = 0; p < 2; p++) {
      int idx = tid + p * 256, row = idx >> 3, seg = idx & 7;
      *(u16x8*)&Ah[0][row][seg * 8] = *(const u16x8*)&Ahi[(size_t)(brow + row) * Cch + k0 + seg * 8];
      *(u16x8*)&Ah[1][row][seg * 8] = *(const u16x8*)&Alo[(size_t)(brow + row) * Cch + k0 + seg * 8];
      *(u16x8*)&Bs[0][row][seg * 8] = *(const u16x8*)&Bhi[(size_t)(bcol + row) * Cch + k0 + seg * 8];
      *(u16x8*)&Bs[1][row][seg * 8] = *(const u16x8*)&Blo[(size_t)(bcol + row) * Cch + k0 + seg * 8];
    }
    __syncthreads();
#pragma unroll
    for (int ks = 0; ks < 2; ks++) {
      s16x8 ah[2], al[2], bh[2], bl[2];
#pragma unroll
      for (int ti = 0; ti < 2; ti++) {
        ah[ti] = *(const s16x8*)&Ah[0][wr * 32 + ti * 16 + lr][ks * 32 + e * 8];
        al[ti] = *(const s16x8*)&Ah[1][wr * 32 + ti * 16 + lr][ks * 32 + e * 8];
      }
#pragma unroll
      for (int tj = 0; tj < 2; tj++) {
        bh[tj] = *(const s16x8*)&Bs[0][wc * 32 + tj * 16 + lr][ks * 32 + e * 8];
        bl[tj] = *(const s16x8*)&Bs[1][wc * 32 + tj * 16 + lr][ks * 32 + e * 8];
      }
#pragma unroll
      for (int ti = 0; ti < 2; ti++)
#pragma unroll
        for (int tj = 0; tj < 2; tj++) {
          acc[ti][tj] = __builtin_amdgcn_mfma_f32_16x16x32_bf16(ah[ti], bh[tj], acc[ti][tj], 0, 0, 0);
          acc[ti][tj] = __builtin_amdgcn_mfma_f32_16x16x32_bf16(ah[ti], bl[tj], acc[ti][tj], 0, 0, 0);
          acc[ti][tj] = __builtin_amdgcn_mfma_f32_16x16x32_bf16(al[ti], bh[tj], acc[ti][tj], 0, 0, 0);
        }
    }
    __syncthreads();
  }
#pragma unroll
  for (int ti = 0; ti < 2; ti++)
#pragma unroll
    for (int tj = 0; tj < 2; tj++) {
      int col = bcol + wc * 32 + tj * 16 + lr;
      float bi = bias[col];
#pragma unroll
      for (int r = 0; r < 4; r++) {
        int row = brow + wr * 32 + ti * 16 + e * 4 + r;
        float v = acc[ti][tj][r] + bi;
        if (BF16OUT) ((unsigned short*)Out)[(size_t)row * Cch + col] = f2bf(v);
        else         ((float*)Out)[(size_t)row * Cch + col] = v;
      }
    }
}

// ---------- V normalize + transpose: Vf[token][C] f32 -> Vt[bh*64+d][t] bf16 ----------
__global__ __launch_bounds__(512) void vnormt_k(const float* __restrict__ Vf,
                                                unsigned short* __restrict__ Vt) {
  int wid = blockIdx.x * 8 + (threadIdx.x >> 6);
  int lane = threadIdx.x & 63;
  int token = wid >> 3, h = wid & 7;
  float v = Vf[(size_t)token * Cch + h * 64 + lane];
  float ss = wave_sum_f(v * v);
  float nrm = fmaxf(sqrtf(ss), 1e-12f);
  int b = token >> 11, t = token & 2047;
  Vt[((size_t)((b * Hc + h) * 64 + lane)) * Tc + t] = f2bf(v / nrm);
}

// ---------- S = (Q K^T)/8 into causal-compact triangular storage ----------
__global__ __launch_bounds__(512) void sqk_k(const unsigned short* __restrict__ Qp,
    const unsigned short* __restrict__ Kp, float* __restrict__ S, int bh0) {
  __shared__ unsigned short Qs[128][72], Ks[128][72];
  int rt, ct;
  {
    int i = blockIdx.x;
    int r = (int)((sqrtf(8.f * i + 1.f) - 1.f) * 0.5f);
    while ((r + 1) * (r + 2) / 2 <= i) r++;
    while (r * (r + 1) / 2 > i) r--;
    rt = r; ct = i - r * (r + 1) / 2;
  }
  const int bh = bh0 + blockIdx.y, b = bh >> 3, h = bh & 7;
  const int tid = threadIdx.x, w = tid >> 6, lane = tid & 63, e = lane >> 4, lr = lane & 15;
#pragma unroll
  for (int p = 0; p < 2; p++) {
    int idx = tid + p * 512, row = idx >> 3, seg = idx & 7;
    *(u16x8*)&Qs[row][seg * 8] = *(const u16x8*)&Qp[((size_t)(b * Tc + rt * 128 + row)) * Cch + h * 64 + seg * 8];
    *(u16x8*)&Ks[row][seg * 8] = *(const u16x8*)&Kp[((size_t)(b * Tc + ct * 128 + row)) * Cch + h * 64 + seg * 8];
  }
  __syncthreads();
  f32x4 acc[8] = {};
  s16x8 a[2];
#pragma unroll
  for (int ks = 0; ks < 2; ks++) a[ks] = *(const s16x8*)&Qs[w * 16 + lr][ks * 32 + e * 8];
#pragma unroll
  for (int tj = 0; tj < 8; tj++) {
#pragma unroll
    for (int ks = 0; ks < 2; ks++) {
      s16x8 bb = *(const s16x8*)&Ks[tj * 16 + lr][ks * 32 + e * 8];
      acc[tj] = __builtin_amdgcn_mfma_f32_16x16x32_bf16(a[ks], bb, acc[tj], 0, 0, 0);
    }
  }
  float* Srow0 = S + (size_t)(bh - bh0) * TRI_FLOATS + (size_t)tri_i(rt) * 16384;
  const int stride = (rt + 1) * 128;
#pragma unroll
  for (int tj = 0; tj < 8; tj++)
#pragma unroll
    for (int r = 0; r < 4; r++) {
      int row = w * 16 + e * 4 + r;
      Srow0[(size_t)row * stride + ct * 128 + tj * 16 + lr] = acc[tj][r] * 0.125f;
    }
}

// ---------- exact top-64 + softmax; writes normalized P bf16 in-place ----------
__global__ __launch_bounds__(512) void sel_k(float* __restrict__ S) {
  int wid = blockIdx.x * 8 + (threadIdx.x >> 6);
  int lane = threadIdx.x & 63;
  int bhl = wid >> 11, t = wid & 2047;
  int rt = t >> 7, lrow = t & 127;
  int stride = (rt + 1) * 128;
  float* row = S + (size_t)bhl * TRI_FLOATS + (size_t)tri_i(rt) * 16384 + (size_t)lrow * stride;
  unsigned su[32];
#pragma unroll
  for (int i = 0; i < 8; i++) {
    int j0 = i * 256 + lane * 4;
    f32x4 v;
    if (j0 < stride) v = *(const f32x4*)(row + j0);
    else { v[0] = v[1] = v[2] = v[3] = -INFINITY; }
#pragma unroll
    for (int c = 0; c < 4; c++) {
      float x = (j0 + c <= t) ? v[c] : -INFINITY;
      unsigned u = __float_as_uint(x);
      su[i * 4 + c] = (u & 0x80000000u) ? ~u : (u | 0x80000000u);
    }
  }
  // radix search for max lo with count(su >= lo) >= 64; early-exit min-refine at cnt==64
  unsigned lo = 0;
#pragma unroll 1
  for (int bit = 31; bit >= 0; bit--) {
    unsigned cand = lo | (1u << bit);
    int cnt = 0;
#pragma unroll
    for (int i = 0; i < 32; i++) cnt += (int)__popcll(__ballot(su[i] >= cand));
    if (cnt >= 64) {
      lo = cand;
      if (cnt == 64) {
        unsigned mn = 0xFFFFFFFFu;
#pragma unroll
        for (int i = 0; i < 32; i++) { unsigned x = (su[i] >= cand) ? su[i] : 0xFFFFFFFFu; mn = mn < x ? mn : x; }
#pragma unroll
        for (int o = 32; o; o >>= 1) { unsigned x = (unsigned)__shfl_xor((int)mn, o); mn = mn < x ? mn : x; }
        lo = mn;
        break;
      }
    }
  }
  unsigned mx = 0;
#pragma unroll
  for (int i = 0; i < 32; i++) mx = mx > su[i] ? mx : su[i];
#pragma unroll
  for (int o = 32; o; o >>= 1) { unsigned x = (unsigned)__shfl_xor((int)mx, o); mx = mx > x ? mx : x; }
  float m = su2f(mx);
  float sum = 0.f;
#pragma unroll
  for (int i = 0; i < 32; i++) {
    float v = su2f(su[i]);
    float wv = (su[i] >= lo) ? __expf(v - m) : 0.f;  // exp(-inf)=0
    su[i] = __float_as_uint(wv);
    sum += wv;
  }
  sum = wave_sum_f(sum);
  float inv = 1.f / sum;
  unsigned short* prow = (unsigned short*)row;
#pragma unroll
  for (int i = 0; i < 8; i++) {
    int j0 = i * 256 + lane * 4;
    if (j0 < stride) {
      u16x4 pk;
#pragma unroll
      for (int c = 0; c < 4; c++) pk[c] = f2bf(__uint_as_float(su[i * 4 + c]) * inv);
      *(u16x4*)(prow + j0) = pk;
    }
  }
}

// ---------- Y = P @ V^T (dense causal MFMA), epilogue splits Y to bf16 hi/lo ----------
__global__ __launch_bounds__(512) void pv_k(const float* __restrict__ S,
    const unsigned short* __restrict__ Vt,
    unsigned short* __restrict__ Yhi, unsigned short* __restrict__ Ylo, int bh0) {
  __shared__ unsigned short Ps[128][136];
  __shared__ unsigned short Vs[64][136];
  const int rt = blockIdx.x, bh = bh0 + blockIdx.y, b = bh >> 3, h = bh & 7;
  const int tid = threadIdx.x, w = tid >> 6, lane = tid & 63, e = lane >> 4, lr = lane & 15;
  const int stride = (rt + 1) * 128;
  const float* Srow0 = S + (size_t)(bh - bh0) * TRI_FLOATS + (size_t)tri_i(rt) * 16384;
  f32x4 acc[4] = {};
  for (int kt = 0; kt <= rt; kt++) {
#pragma unroll
    for (int p = 0; p < 4; p++) {
      int idx = tid + p * 512, row = idx >> 4, seg = idx & 15;
      const unsigned short* src = (const unsigned short*)(Srow0 + (size_t)row * stride) + kt * 128 + seg * 8;
      *(u16x8*)&Ps[row][seg * 8] = *(const u16x8*)src;
    }
#pragma unroll
    for (int p = 0; p < 2; p++) {
      int idx = tid + p * 512, d = idx >> 4, seg = idx & 15;
      *(u16x8*)&Vs[d][seg * 8] = *(const u16x8*)&Vt[((size_t)(bh * 64 + d)) * Tc + kt * 128 + seg * 8];
    }
    __syncthreads();
#pragma unroll
    for (int ks = 0; ks < 4; ks++) {
      s16x8 a = *(const s16x8*)&Ps[w * 16 + lr][ks * 32 + e * 8];
#pragma unroll
      for (int tj = 0; tj < 4; tj++) {
        s16x8 bb = *(const s16x8*)&Vs[tj * 16 + lr][ks * 32 + e * 8];
        acc[tj] = __builtin_amdgcn_mfma_f32_16x16x32_bf16(a, bb, acc[tj], 0, 0, 0);
      }
    }
    __syncthreads();
  }
#pragma unroll
  for (int tj = 0; tj < 4; tj++)
#pragma unroll
    for (int r = 0; r < 4; r++) {
      int row = rt * 128 + w * 16 + e * 4 + r;
      size_t g = ((size_t)(b * Tc + row)) * Cch + h * 64 + tj * 16 + lr;
      float y = acc[tj][r];
      unsigned short hh = f2bf(y);
      Yhi[g] = hh;
      Ylo[g] = f2bf(y - bf2f(hh));
    }
}

extern "C" void kernel_launch(void* const* d_in, const int* in_sizes, int n_in,
                              void* d_out, int out_size, void* d_ws, size_t ws_size,
                              hipStream_t stream) {
  const float* q  = (const float*)d_in[0];
  // d_in[1] = tgt_mask: pure causal tril, handled analytically
  const float* Wq = (const float*)d_in[2];
  const float* bq = (const float*)d_in[3];
  const float* Wk = (const float*)d_in[4];
  const float* bk = (const float*)d_in[5];
  const float* Wv = (const float*)d_in[6];
  const float* bv = (const float*)d_in[7];
  const float* Wp = (const float*)d_in[8];
  const float* bp = (const float*)d_in[9];
  float* out = (float*)d_out;
  char* ws = (char*)d_ws;
  constexpr size_t MB = 1u << 20;

  unsigned short* qhi = (unsigned short*)(ws + 0 * MB);   // 4 MB (later Yhi)
  unsigned short* qlo = (unsigned short*)(ws + 4 * MB);   // 4 MB (later Ylo)
  unsigned short* Qp  = (unsigned short*)(ws + 8 * MB);   // 4 MB
  unsigned short* Kp  = (unsigned short*)(ws + 12 * MB);  // 4 MB
  unsigned short* Vt  = (unsigned short*)(ws + 16 * MB);  // 4 MB
  unsigned short* wsp = (unsigned short*)(ws + 20 * MB);  // 8 x 512 KB weight splits
  float* Sb = (float*)(ws + 24 * MB);                     // S/P region (chunked)
  float* Vf = (float*)(ws + 24 * MB);                     // overlays S (consumed first)
  unsigned short* Yhi = qhi;
  unsigned short* Ylo = qlo;
  auto WT = [&](int i) { return wsp + (size_t)i * 262144; };

  // deterministic per-environment chunking of the S buffer
  int nbh = NBH;
  while (nbh > 1 && 24 * MB + TRI_FLOATS * 4 * (size_t)nbh > ws_size) nbh >>= 1;

  split_k<<<(BT * Cch / 8 + 255) / 256, 256, 0, stream>>>(q, qhi, qlo, BT * Cch / 8);
  dim3 g8(8, 8);
  splitT_k<<<g8, 256, 0, stream>>>(Wq, WT(0), WT(1));
  splitT_k<<<g8, 256, 0, stream>>>(Wk, WT(2), WT(3));
  splitT_k<<<g8, 256, 0, stream>>>(Wv, WT(4), WT(5));
  splitT_k<<<g8, 256, 0, stream>>>(Wp, WT(6), WT(7));

  dim3 gp(Cch / 64, BT / 64);  // (8, 64)
  gemm3_k<1><<<gp, 256, 0, stream>>>(qhi, qlo, WT(0), WT(1), bq, Qp);
  gemm3_k<1><<<gp, 256, 0, stream>>>(qhi, qlo, WT(2), WT(3), bk, Kp);
  gemm3_k<0><<<gp, 256, 0, stream>>>(qhi, qlo, WT(4), WT(5), bv, Vf);
  vnormt_k<<<BT * Hc / 8, 512, 0, stream>>>(Vf, Vt);

  for (int c = 0; c < NBH / nbh; c++) {
    int bh0 = c * nbh;
    sqk_k<<<dim3(NTRI, nbh), 512, 0, stream>>>(Qp, Kp, Sb, bh0);
    sel_k<<<nbh * 256, 512, 0, stream>>>(Sb);
    pv_k<<<dim3(NRT, nbh), 512, 0, stream>>>(Sb, Vt, Yhi, Ylo, bh0);
  }

  gemm3_k<0><<<gp, 256, 0, stream>>>(Yhi, Ylo, WT(6), WT(7), bp, out);
}

// Round 6
// 225.789 us; speedup vs baseline: 6.9937x; 1.1208x over previous
//
#include <hip/hip_runtime.h>
#include <cstdint>
#include <math.h>

static constexpr int Bc = 2, Tc = 2048, Cch = 512, Hc = 8;
static constexpr int BT = Bc * Tc;          // 4096
static constexpr int NBH = Bc * Hc;         // 16
static constexpr int NRT = Tc / 128;        // 16 row-tiles per (b,h)
static constexpr int NTRI = NRT * (NRT + 1) / 2;  // 136 causal blocks
static constexpr size_t TRI_FLOATS = (size_t)NTRI * 16384;  // f32 per (b,h)

typedef float f32x4 __attribute__((ext_vector_type(4)));
typedef short s16x8 __attribute__((ext_vector_type(8)));
typedef unsigned short u16x8 __attribute__((ext_vector_type(8)));
typedef unsigned short u16x4 __attribute__((ext_vector_type(4)));

__device__ __host__ inline constexpr int tri_i(int r) { return r * (r + 1) / 2; }

__device__ inline float wave_sum_f(float x) {
#pragma unroll
  for (int o = 32; o; o >>= 1) x += __shfl_xor(x, o);
  return x;
}
__device__ inline unsigned short f2bf(float x) {  // RNE f32->bf16 (finite)
  unsigned u = __float_as_uint(x);
  return (unsigned short)((u + 0x7FFFu + ((u >> 16) & 1u)) >> 16);
}
__device__ inline float bf2f(unsigned short h) { return __uint_as_float(((unsigned)h) << 16); }
__device__ inline float su2f(unsigned s) {  // inverse order-preserving map
  unsigned u = (s & 0x80000000u) ? (s ^ 0x80000000u) : ~s;
  return __uint_as_float(u);
}

// ---------- split f32 -> bf16 hi/lo ----------
__global__ __launch_bounds__(256) void split_k(const float* __restrict__ X,
    unsigned short* __restrict__ hi, unsigned short* __restrict__ lo, int n8) {
  int i = blockIdx.x * 256 + threadIdx.x;
  if (i >= n8) return;
  const f32x4* p = (const f32x4*)X + (size_t)i * 2;
  f32x4 a = p[0], b = p[1];
  float v[8] = {a[0], a[1], a[2], a[3], b[0], b[1], b[2], b[3]};
  u16x8 h, l;
#pragma unroll
  for (int c = 0; c < 8; c++) {
    unsigned short hh = f2bf(v[c]);
    h[c] = hh;
    l[c] = f2bf(v[c] - bf2f(hh));
  }
  *(u16x8*)(hi + (size_t)i * 8) = h;
  *(u16x8*)(lo + (size_t)i * 8) = l;
}

// ---------- split + transpose weights: W[k][n] f32 -> WT[n][k] bf16 hi/lo ----------
__global__ __launch_bounds__(256) void splitT_k(const float* __restrict__ W,
    unsigned short* __restrict__ hiT, unsigned short* __restrict__ loT) {
  __shared__ float t[64][65];
  const int tid = threadIdx.x;
  const int k0 = blockIdx.x * 64, n0 = blockIdx.y * 64;
#pragma unroll
  for (int p = 0; p < 4; p++) {
    int idx = tid + p * 256, kk = idx >> 4, n4 = idx & 15;
    f32x4 v = *(const f32x4*)&W[(size_t)(k0 + kk) * Cch + n0 + n4 * 4];
    t[kk][n4 * 4 + 0] = v[0]; t[kk][n4 * 4 + 1] = v[1];
    t[kk][n4 * 4 + 2] = v[2]; t[kk][n4 * 4 + 3] = v[3];
  }
  __syncthreads();
  // write phase: exactly 64 n-values x 4 k-segments = 256 items, ONE pass
  {
    int n = tid >> 2, ks = tid & 3;
    u16x8 h0, h1, l0, l1;
#pragma unroll
    for (int kk = 0; kk < 8; kk++) {
      float x = t[ks * 16 + kk][n];
      unsigned short hh = f2bf(x);
      h0[kk] = hh; l0[kk] = f2bf(x - bf2f(hh));
      float y = t[ks * 16 + 8 + kk][n];
      unsigned short hy = f2bf(y);
      h1[kk] = hy; l1[kk] = f2bf(y - bf2f(hy));
    }
    size_t base = (size_t)(n0 + n) * Cch + k0 + ks * 16;
    *(u16x8*)(hiT + base) = h0; *(u16x8*)(hiT + base + 8) = h1;
    *(u16x8*)(loT + base) = l0; *(u16x8*)(loT + base + 8) = l1;
  }
}

// ---------- bf16x3 MFMA GEMM: Out[M=4096][512] = (Ahi+Alo)@(BT)^T + bias ----------
template <int BF16OUT>
__global__ __launch_bounds__(256) void gemm3_k(
    const unsigned short* __restrict__ Ahi, const unsigned short* __restrict__ Alo,
    const unsigned short* __restrict__ Bhi, const unsigned short* __restrict__ Blo,
    const float* __restrict__ bias, void* __restrict__ Out) {
  __shared__ unsigned short Ah[2][64][72];
  __shared__ unsigned short Bs[2][64][72];
  const int tid = threadIdx.x;
  const int w = tid >> 6, lane = tid & 63, e = lane >> 4, lr = lane & 15;
  const int wr = w >> 1, wc = w & 1;
  const int brow = blockIdx.y * 64, bcol = blockIdx.x * 64;
  f32x4 acc[2][2] = {};
  for (int k0 = 0; k0 < Cch; k0 += 64) {
#pragma unroll
    for (int p = 0; p < 2; p++) {
      int idx = tid + p * 256, row = idx >> 3, seg = idx & 7;
      *(u16x8*)&Ah[0][row][seg * 8] = *(const u16x8*)&Ahi[(size_t)(brow + row) * Cch + k0 + seg * 8];
      *(u16x8*)&Ah[1][row][seg * 8] = *(const u16x8*)&Alo[(size_t)(brow + row) * Cch + k0 + seg * 8];
      *(u16x8*)&Bs[0][row][seg * 8] = *(const u16x8*)&Bhi[(size_t)(bcol + row) * Cch + k0 + seg * 8];
      *(u16x8*)&Bs[1][row][seg * 8] = *(const u16x8*)&Blo[(size_t)(bcol + row) * Cch + k0 + seg * 8];
    }
    __syncthreads();
#pragma unroll
    for (int ks = 0; ks < 2; ks++) {
      s16x8 ah[2], al[2], bh[2], bl[2];
#pragma unroll
      for (int ti = 0; ti < 2; ti++) {
        ah[ti] = *(const s16x8*)&Ah[0][wr * 32 + ti * 16 + lr][ks * 32 + e * 8];
        al[ti] = *(const s16x8*)&Ah[1][wr * 32 + ti * 16 + lr][ks * 32 + e * 8];
      }
#pragma unroll
      for (int tj = 0; tj < 2; tj++) {
        bh[tj] = *(const s16x8*)&Bs[0][wc * 32 + tj * 16 + lr][ks * 32 + e * 8];
        bl[tj] = *(const s16x8*)&Bs[1][wc * 32 + tj * 16 + lr][ks * 32 + e * 8];
      }
#pragma unroll
      for (int ti = 0; ti < 2; ti++)
#pragma unroll
        for (int tj = 0; tj < 2; tj++) {
          acc[ti][tj] = __builtin_amdgcn_mfma_f32_16x16x32_bf16(ah[ti], bh[tj], acc[ti][tj], 0, 0, 0);
          acc[ti][tj] = __builtin_amdgcn_mfma_f32_16x16x32_bf16(ah[ti], bl[tj], acc[ti][tj], 0, 0, 0);
          acc[ti][tj] = __builtin_amdgcn_mfma_f32_16x16x32_bf16(al[ti], bh[tj], acc[ti][tj], 0, 0, 0);
        }
    }
    __syncthreads();
  }
#pragma unroll
  for (int ti = 0; ti < 2; ti++)
#pragma unroll
    for (int tj = 0; tj < 2; tj++) {
      int col = bcol + wc * 32 + tj * 16 + lr;
      float bi = bias[col];
#pragma unroll
      for (int r = 0; r < 4; r++) {
        int row = brow + wr * 32 + ti * 16 + e * 4 + r;
        float v = acc[ti][tj][r] + bi;
        if (BF16OUT) ((unsigned short*)Out)[(size_t)row * Cch + col] = f2bf(v);
        else         ((float*)Out)[(size_t)row * Cch + col] = v;
      }
    }
}

// ---------- V normalize + transpose via LDS: Vf[token][C] f32 -> Vt[bh*64+d][t] bf16 ----------
__global__ __launch_bounds__(256) void vnormt_k(const float* __restrict__ Vf,
                                                unsigned short* __restrict__ Vt) {
  __shared__ unsigned short T[64][72];  // [d][token] bf16
  const int tid = threadIdx.x;
  const int t0 = blockIdx.x * 64;       // 64 tokens per block
  const int h = blockIdx.y;
  const int tok = tid >> 2;             // local token 0..63
  const int q = tid & 3;                // d-quad: 16 d's
  const float* src = Vf + (size_t)(t0 + tok) * Cch + h * 64 + q * 16;
  f32x4 v[4];
  float ss = 0.f;
#pragma unroll
  for (int i = 0; i < 4; i++) {
    v[i] = *(const f32x4*)(src + i * 4);
#pragma unroll
    for (int c = 0; c < 4; c++) ss += v[i][c] * v[i][c];
  }
  ss += __shfl_xor(ss, 1);
  ss += __shfl_xor(ss, 2);  // 4-lane group = one token's 64 d's
  float inv = 1.0f / fmaxf(sqrtf(ss), 1e-12f);
#pragma unroll
  for (int i = 0; i < 4; i++)
#pragma unroll
    for (int c = 0; c < 4; c++)
      T[q * 16 + i * 4 + c][tok] = f2bf(v[i][c] * inv);
  __syncthreads();
  const int d = tid >> 2, s2 = (tid & 3) * 2;
  const int b = t0 >> 11;
  size_t base = ((size_t)((b * Hc + h) * 64 + d)) * Tc + (t0 & 2047);
  *(u16x8*)(Vt + base + s2 * 8)     = *(const u16x8*)&T[d][s2 * 8];
  *(u16x8*)(Vt + base + s2 * 8 + 8) = *(const u16x8*)&T[d][s2 * 8 + 8];
}

// ---------- S = (Q K^T)/8 into causal-compact triangular storage ----------
__global__ __launch_bounds__(512) void sqk_k(const unsigned short* __restrict__ Qp,
    const unsigned short* __restrict__ Kp, float* __restrict__ S, int bh0) {
  __shared__ unsigned short Qs[128][72], Ks[128][72];
  int rt, ct;
  {
    int i = blockIdx.x;
    int r = (int)((sqrtf(8.f * i + 1.f) - 1.f) * 0.5f);
    while ((r + 1) * (r + 2) / 2 <= i) r++;
    while (r * (r + 1) / 2 > i) r--;
    rt = r; ct = i - r * (r + 1) / 2;
  }
  const int bh = bh0 + blockIdx.y, b = bh >> 3, h = bh & 7;
  const int tid = threadIdx.x, w = tid >> 6, lane = tid & 63, e = lane >> 4, lr = lane & 15;
#pragma unroll
  for (int p = 0; p < 2; p++) {
    int idx = tid + p * 512, row = idx >> 3, seg = idx & 7;
    *(u16x8*)&Qs[row][seg * 8] = *(const u16x8*)&Qp[((size_t)(b * Tc + rt * 128 + row)) * Cch + h * 64 + seg * 8];
    *(u16x8*)&Ks[row][seg * 8] = *(const u16x8*)&Kp[((size_t)(b * Tc + ct * 128 + row)) * Cch + h * 64 + seg * 8];
  }
  __syncthreads();
  f32x4 acc[8] = {};
  s16x8 a[2];
#pragma unroll
  for (int ks = 0; ks < 2; ks++) a[ks] = *(const s16x8*)&Qs[w * 16 + lr][ks * 32 + e * 8];
#pragma unroll
  for (int tj = 0; tj < 8; tj++) {
#pragma unroll
    for (int ks = 0; ks < 2; ks++) {
      s16x8 bb = *(const s16x8*)&Ks[tj * 16 + lr][ks * 32 + e * 8];
      acc[tj] = __builtin_amdgcn_mfma_f32_16x16x32_bf16(a[ks], bb, acc[tj], 0, 0, 0);
    }
  }
  float* Srow0 = S + (size_t)(bh - bh0) * TRI_FLOATS + (size_t)tri_i(rt) * 16384;
  const int stride = (rt + 1) * 128;
#pragma unroll
  for (int tj = 0; tj < 8; tj++)
#pragma unroll
    for (int r = 0; r < 4; r++) {
      int row = w * 16 + e * 4 + r;
      Srow0[(size_t)row * stride + ct * 128 + tj * 16 + lr] = acc[tj][r] * 0.125f;
    }
}

// ---------- exact top-64 + softmax; writes normalized P bf16 in-place ----------
// chunk-guarded: radix/exp work only over the causal-compact stride
__global__ __launch_bounds__(512) void sel_k(float* __restrict__ S) {
  int wid = blockIdx.x * 8 + (threadIdx.x >> 6);
  int lane = threadIdx.x & 63;
  int bhl = wid >> 11, t = wid & 2047;
  int rt = t >> 7, lrow = t & 127;
  int stride = (rt + 1) * 128;
  float* row = S + (size_t)bhl * TRI_FLOATS + (size_t)tri_i(rt) * 16384 + (size_t)lrow * stride;
  unsigned su[32];
#pragma unroll
  for (int c = 0; c < 8; c++) {
    if (c * 256 < stride) {
      int j0 = c * 256 + lane * 4;
      f32x4 v;
      if (j0 < stride) v = *(const f32x4*)(row + j0);
      else { v[0] = v[1] = v[2] = v[3] = -INFINITY; }
#pragma unroll
      for (int cc = 0; cc < 4; cc++) {
        float x = (j0 + cc <= t) ? v[cc] : -INFINITY;
        unsigned u = __float_as_uint(x);
        su[c * 4 + cc] = (u & 0x80000000u) ? ~u : (u | 0x80000000u);
      }
    } else {
#pragma unroll
      for (int cc = 0; cc < 4; cc++) su[c * 4 + cc] = 0x007FFFFFu;  // map(-inf)
    }
  }
  // radix search for max lo with count(su >= lo) >= 64; early-exit min-refine at cnt==64
  unsigned lo = 0;
#pragma unroll 1
  for (int bit = 31; bit >= 0; bit--) {
    unsigned cand = lo | (1u << bit);
    int cnt = 0;
#pragma unroll
    for (int c = 0; c < 8; c++)
      if (c * 256 < stride)
#pragma unroll
        for (int q = 0; q < 4; q++)
          cnt += (int)__popcll(__ballot(su[c * 4 + q] >= cand));
    if (cnt >= 64) {
      lo = cand;
      if (cnt == 64) {
        unsigned mn = 0xFFFFFFFFu;
#pragma unroll
        for (int c = 0; c < 8; c++)
          if (c * 256 < stride)
#pragma unroll
            for (int q = 0; q < 4; q++) { unsigned x = (su[c * 4 + q] >= cand) ? su[c * 4 + q] : 0xFFFFFFFFu; mn = mn < x ? mn : x; }
#pragma unroll
        for (int o = 32; o; o >>= 1) { unsigned x = (unsigned)__shfl_xor((int)mn, o); mn = mn < x ? mn : x; }
        lo = mn;
        break;
      }
    }
  }
  unsigned mx = 0;
#pragma unroll
  for (int c = 0; c < 8; c++)
    if (c * 256 < stride)
#pragma unroll
      for (int q = 0; q < 4; q++) mx = mx > su[c * 4 + q] ? mx : su[c * 4 + q];
#pragma unroll
  for (int o = 32; o; o >>= 1) { unsigned x = (unsigned)__shfl_xor((int)mx, o); mx = mx > x ? mx : x; }
  float m = su2f(mx);
  float sum = 0.f;
#pragma unroll
  for (int c = 0; c < 8; c++)
    if (c * 256 < stride)
#pragma unroll
      for (int q = 0; q < 4; q++) {
        float v = su2f(su[c * 4 + q]);
        float wv = (su[c * 4 + q] >= lo) ? __expf(v - m) : 0.f;  // exp(-inf)=0
        su[c * 4 + q] = __float_as_uint(wv);
        sum += wv;
      }
  sum = wave_sum_f(sum);
  float inv = 1.f / sum;
  unsigned short* prow = (unsigned short*)row;
#pragma unroll
  for (int c = 0; c < 8; c++) {
    if (c * 256 < stride) {
      int j0 = c * 256 + lane * 4;
      if (j0 < stride) {
        u16x4 pk;
#pragma unroll
        for (int cc = 0; cc < 4; cc++) pk[cc] = f2bf(__uint_as_float(su[c * 4 + cc]) * inv);
        *(u16x4*)(prow + j0) = pk;
      }
    }
  }
}

// ---------- Y = P @ V^T (dense causal MFMA), epilogue splits Y to bf16 hi/lo ----------
__global__ __launch_bounds__(512) void pv_k(const float* __restrict__ S,
    const unsigned short* __restrict__ Vt,
    unsigned short* __restrict__ Yhi, unsigned short* __restrict__ Ylo, int bh0) {
  __shared__ unsigned short Ps[128][136];
  __shared__ unsigned short Vs[64][136];
  const int rt = blockIdx.x, bh = bh0 + blockIdx.y, b = bh >> 3, h = bh & 7;
  const int tid = threadIdx.x, w = tid >> 6, lane = tid & 63, e = lane >> 4, lr = lane & 15;
  const int stride = (rt + 1) * 128;
  const float* Srow0 = S + (size_t)(bh - bh0) * TRI_FLOATS + (size_t)tri_i(rt) * 16384;
  f32x4 acc[4] = {};
  for (int kt = 0; kt <= rt; kt++) {
#pragma unroll
    for (int p = 0; p < 4; p++) {
      int idx = tid + p * 512, row = idx >> 4, seg = idx & 15;
      const unsigned short* src = (const unsigned short*)(Srow0 + (size_t)row * stride) + kt * 128 + seg * 8;
      *(u16x8*)&Ps[row][seg * 8] = *(const u16x8*)src;
    }
#pragma unroll
    for (int p = 0; p < 2; p++) {
      int idx = tid + p * 512, d = idx >> 4, seg = idx & 15;
      *(u16x8*)&Vs[d][seg * 8] = *(const u16x8*)&Vt[((size_t)(bh * 64 + d)) * Tc + kt * 128 + seg * 8];
    }
    __syncthreads();
#pragma unroll
    for (int ks = 0; ks < 4; ks++) {
      s16x8 a = *(const s16x8*)&Ps[w * 16 + lr][ks * 32 + e * 8];
#pragma unroll
      for (int tj = 0; tj < 4; tj++) {
        s16x8 bb = *(const s16x8*)&Vs[tj * 16 + lr][ks * 32 + e * 8];
        acc[tj] = __builtin_amdgcn_mfma_f32_16x16x32_bf16(a, bb, acc[tj], 0, 0, 0);
      }
    }
    __syncthreads();
  }
#pragma unroll
  for (int tj = 0; tj < 4; tj++)
#pragma unroll
    for (int r = 0; r < 4; r++) {
      int row = rt * 128 + w * 16 + e * 4 + r;
      size_t g = ((size_t)(b * Tc + row)) * Cch + h * 64 + tj * 16 + lr;
      float y = acc[tj][r];
      unsigned short hh = f2bf(y);
      Yhi[g] = hh;
      Ylo[g] = f2bf(y - bf2f(hh));
    }
}

extern "C" void kernel_launch(void* const* d_in, const int* in_sizes, int n_in,
                              void* d_out, int out_size, void* d_ws, size_t ws_size,
                              hipStream_t stream) {
  const float* q  = (const float*)d_in[0];
  // d_in[1] = tgt_mask: pure causal tril, handled analytically
  const float* Wq = (const float*)d_in[2];
  const float* bq = (const float*)d_in[3];
  const float* Wk = (const float*)d_in[4];
  const float* bk = (const float*)d_in[5];
  const float* Wv = (const float*)d_in[6];
  const float* bv = (const float*)d_in[7];
  const float* Wp = (const float*)d_in[8];
  const float* bp = (const float*)d_in[9];
  float* out = (float*)d_out;
  char* ws = (char*)d_ws;
  constexpr size_t MB = 1u << 20;

  unsigned short* qhi = (unsigned short*)(ws + 0 * MB);   // 4 MB (later Yhi)
  unsigned short* qlo = (unsigned short*)(ws + 4 * MB);   // 4 MB (later Ylo)
  unsigned short* Qp  = (unsigned short*)(ws + 8 * MB);   // 4 MB
  unsigned short* Kp  = (unsigned short*)(ws + 12 * MB);  // 4 MB
  unsigned short* Vt  = (unsigned short*)(ws + 16 * MB);  // 4 MB
  unsigned short* wsp = (unsigned short*)(ws + 20 * MB);  // 8 x 512 KB weight splits
  float* Sb = (float*)(ws + 24 * MB);                     // S/P region (chunked)
  float* Vf = (float*)(ws + 24 * MB);                     // overlays S (consumed first)
  unsigned short* Yhi = qhi;
  unsigned short* Ylo = qlo;
  auto WT = [&](int i) { return wsp + (size_t)i * 262144; };

  // deterministic per-environment chunking of the S buffer
  int nbh = NBH;
  while (nbh > 1 && 24 * MB + TRI_FLOATS * 4 * (size_t)nbh > ws_size) nbh >>= 1;

  split_k<<<(BT * Cch / 8 + 255) / 256, 256, 0, stream>>>(q, qhi, qlo, BT * Cch / 8);
  dim3 g8(8, 8);
  splitT_k<<<g8, 256, 0, stream>>>(Wq, WT(0), WT(1));
  splitT_k<<<g8, 256, 0, stream>>>(Wk, WT(2), WT(3));
  splitT_k<<<g8, 256, 0, stream>>>(Wv, WT(4), WT(5));
  splitT_k<<<g8, 256, 0, stream>>>(Wp, WT(6), WT(7));

  dim3 gp(Cch / 64, BT / 64);  // (8, 64)
  gemm3_k<1><<<gp, 256, 0, stream>>>(qhi, qlo, WT(0), WT(1), bq, Qp);
  gemm3_k<1><<<gp, 256, 0, stream>>>(qhi, qlo, WT(2), WT(3), bk, Kp);
  gemm3_k<0><<<gp, 256, 0, stream>>>(qhi, qlo, WT(4), WT(5), bv, Vf);
  vnormt_k<<<dim3(BT / 64, Hc), 256, 0, stream>>>(Vf, Vt);

  for (int c = 0; c < NBH / nbh; c++) {
    int bh0 = c * nbh;
    sqk_k<<<dim3(NTRI, nbh), 512, 0, stream>>>(Qp, Kp, Sb, bh0);
    sel_k<<<nbh * 256, 512, 0, stream>>>(Sb);
    pv_k<<<dim3(NRT, nbh), 512, 0, stream>>>(Sb, Vt, Yhi, Ylo, bh0);
  }

  gemm3_k<0><<<gp, 256, 0, stream>>>(Yhi, Ylo, WT(6), WT(7), bp, out);
}